// Round 16
// baseline (222.418 us; speedup 1.0000x reference)
//
#include <hip/hip_runtime.h>
#include <hip/hip_fp16.h>

#define HH 256
#define WW 256
#define NB 64
#define NPIX (NB * HH * WW)      // 4,194,304 pixels
#define NF4  (NPIX / 4)          // 1,048,576 groups of 4
#define ROW4 (WW / 4)            // 64 groups per image row
#define EPSF 1e-12f
#define FTRH 8                   // output rows per tile
#define FTHR 512                 // 8 waves -> 8 rows per pass
#define TPI  (HH / FTRH)         // 32 tiles per image
#define FBLK (NB * TPI)          // 2048 blocks (FP kernel)
#define NIT  3                   // solver iterations fused per FP launch
#define NU   (FTRH + 2 * NIT)        // 14 LDS u rows
#define NPR  (FTRH + 2 * NIT - 1)    // 13 LDS p rows
// Round-15 structure (proven 214.4): shifting row ownership, fp16 LDS,
// 40 KB -> 4 blocks/CU, XCD-chunked block swizzle, 2-pass unrolled loops.
// This round: the ga/rc side-channel is DELETED. ga=(gx,gy),rc=y-x is a
// pure function of x,y; ALL kernels recompute it per u-step via garc_row
// (bit-identical: gaP stored already-fp16-quantized values, rc same fp32
// ops on same inputs). FP1 loses its 33.6 MB ga/rc store; x,y (33.6 MB)
// is L3-resident and L2-local under the swizzle.

__device__ __forceinline__ float4 ld4(const float* p, int f) {
    return ((const float4*)p)[f];
}
__device__ __forceinline__ void st4(float* p, int f, const float* v) {
    ((float4*)p)[f] = make_float4(v[0], v[1], v[2], v[3]);
}
// Packed-pair load: 4 pixels of a __half2 field (16B) -> two float[4]
__device__ __forceinline__ void ld8h(const __half2* p, int f, float* a, float* b) {
    float4 raw = ((const float4*)p)[f];
    const __half2* h = (const __half2*)&raw;
    #pragma unroll
    for (int k = 0; k < 4; ++k) {
        float2 v = __half22float2(h[k]);
        a[k] = v.x; b[k] = v.y;
    }
}
__device__ __forceinline__ void st8h(__half2* p, int f, const float* a, const float* b) {
    float4 raw;
    __half2* h = (__half2*)&raw;
    #pragma unroll
    for (int k = 0; k < 4; ++k) h[k] = __floats2half2_rn(a[k], b[k]);
    ((float4*)p)[f] = raw;
}
// Pack 4 px of two fields into 4 __half2 inside a float4 (for LDS 16B store)
__device__ __forceinline__ float4 pack4h2(const float* a, const float* b) {
    float4 raw;
    __half2* h = (__half2*)&raw;
    #pragma unroll
    for (int k = 0; k < 4; ++k) h[k] = __floats2half2_rn(a[k], b[k]);
    return raw;
}
__device__ __forceinline__ void unpack4h2(float4 raw, float* a, float* b) {
    const __half2* h = (const __half2*)&raw;
    #pragma unroll
    for (int k = 0; k < 4; ++k) {
        float2 v = __half22float2(h[k]);
        a[k] = v.x; b[k] = v.y;
    }
}
// Extract (a,b) floats from a raw 32-bit half2 word.
__device__ __forceinline__ void h2w(unsigned int w, float& a, float& b) {
    __half2 h = *(__half2*)&w;
    float2 v = __half22float2(h);
    a = v.x; b = v.y;
}

// TV-L1 thresholding step, branch-free:
//   v = med3(-rho/grad, -l_t, l_t) * g   — agrees exactly with the 3-mask
// reference logic. grad >= EPSF so rcp is safe.
__device__ __forceinline__ void thresh(
    float gx, float gy, float rho, float grad, float l_t,
    float& v1, float& v2)
{
    float s = -rho * __builtin_amdgcn_rcpf(grad);
    float c = __builtin_amdgcn_fmed3f(s, -l_t, l_t);
    v1 = c * gx; v2 = c * gy;
}

// p-pair update at one pixel for one flow (approx sqrt/rcp: err ~2^-22,
// far below the fp16 quantization every state field already pays).
__device__ __forceinline__ void pupd(
    float pao, float pbo, float ux, float uy, float taut,
    float& pa, float& pb)
{
    float n2 = fmaf(ux, ux, fmaf(uy, uy, EPSF));
    float n  = __builtin_amdgcn_sqrtf(n2);
    float r  = __builtin_amdgcn_rcpf(fmaf(taut, n, 1.f));
    pa = fmaf(taut, ux, pao) * r;
    pb = fmaf(taut, uy, pbo) * r;
}

// Compute ga=(gx,gy) (fp16-quantized) and rc=y-x (fp32) for global row gr
// from x,y. Wave spans the full row: column neighbors via shuffles.
// Pure function of inputs -> identical values in every kernel/launch.
__device__ __forceinline__ void garc_row(
    const float* __restrict__ xg, const float* __restrict__ yg,
    int f, int gr, int tc, float* gx, float* gy, float* rcv)
{
    float4 xc4 = ld4(xg, f), yc4 = ld4(yg, f);
    const float* xc = (const float*)&xc4;
    const float* yc = (const float*)&yc4;
    float4 a4, b4;                       // wave-uniform row branch
    if (gr == 0)           { a4 = ld4(xg, f + ROW4); b4 = xc4; }
    else if (gr == HH - 1) { a4 = xc4; b4 = ld4(xg, f - ROW4); }
    else                   { a4 = ld4(yg, f + ROW4); b4 = ld4(yg, f - ROW4); }
    const float* aa = (const float*)&a4;
    const float* bb = (const float*)&b4;
    float yl = __shfl_up(yc4.w, 1);      // lane 0 value unused (j==0)
    float yr = __shfl_down(yc4.x, 1);    // lane 63 value unused (j==WW-1)
    #pragma unroll
    for (int k = 0; k < 4; ++k) {
        int j = tc + k;
        float g;
        if (j == 0)            g = 0.5f * (xc[1] - xc[0]);
        else if (j == WW - 1)  g = 0.5f * (xc[3] - xc[2]);
        else {
            float ynext = (k < 3) ? yc[k + 1] : yr;
            float yprev = (k > 0) ? yc[k - 1] : yl;
            g = 0.5f * (ynext - yprev);
        }
        float gyv = 0.5f * (aa[k] - bb[k]);
        // fp16-quantize so all launches see identical gx/gy values
        gx[k] = __half2float(__float2half_rn(g));
        gy[k] = __half2float(__float2half_rn(gyv));
        rcv[k] = yc[k] - xc[k];
    }
}

// ---------------------------------------------------------------------------
// FP: 3 fused solver iterations over an 8-row x 256-col tile with halo
// recompute, shifting row ownership. One wave owns a full row per row-pass;
// left/right px neighbors travel by lane shuffle.
//   sU  : (u1,u2) fp16x2, rows rel [-3, 10]. In-place u-update (same-px).
//   sPA : (p11,p21), sPB : (p12,p22), rows rel [-3, 9]. In-place p-update.
// All row loops are explicit 2-pass unrolled; all kernels recompute ga/rc
// from x,y per u-step (no ga/rc buffers exist).
// P0: u(1)=thresh in prologue, p(k-1)=0. LAST: fp32 u out, p store skipped.
// ---------------------------------------------------------------------------
template <bool P0, bool LAST>
__global__ __launch_bounds__(FTHR, 8) void fp_kernel(
    const __half2* __restrict__ upi,
    const __half2* __restrict__ pai, const __half2* __restrict__ pbi,
    __half2* __restrict__ upo,
    float* __restrict__ u1f, float* __restrict__ u2f,
    __half2* __restrict__ pao, __half2* __restrict__ pbo,
    const float* __restrict__ tp, const float* __restrict__ lp,
    const float* __restrict__ ap,
    const float* __restrict__ xg, const float* __restrict__ yg)
{
    __shared__ alignas(16) __half2 sU [NU ][WW];
    __shared__ alignas(16) __half2 sPA[NPR][WW];
    __shared__ alignas(16) __half2 sPB[NPR][WW];

    const float ts   = tp[0];
    const float l_t  = lp[0] * ts;
    const float taut = ap[0] / ts;

    const int t     = threadIdx.x;
    // XCD-chunked swizzle: HW assigns blockIdx round-robin across 8 XCDs;
    // remap so each XCD gets a contiguous 256-tile chunk -> adjacent tiles
    // (which share halo rows) are co-resident in one XCD's L2. Bijective
    // (FBLK = 2048 = 8 * 256). Perf-only: any mapping is correct.
    const int bid   = blockIdx.x;
    const int tile  = ((bid & 7) << 8) | (bid >> 3);
    const int i0    = (tile & (TPI - 1)) * FTRH;   // tile top row
    const int base4 = (tile / TPI) * (HH * ROW4);  // batch offset, float4 units

    const int tr  = t >> 6;       // wave index 0..7 = row within pass
    const int tcg = t & 63;       // lane
    const int tc  = tcg * 4;

    // ---- prologue: u(k) -> sU rows [-3, 10] (2-pass unrolled) ----
    #pragma unroll
    for (int pass = 0; pass < 2; ++pass) {
        int rr = tr - NIT + pass * FTRH;
        if (rr > FTRH + NIT - 1) continue;        // wave-uniform guard
        int gr = i0 + rr;
        float4* dst = (float4*)&sU[rr + NIT][tc];
        if (gr >= 0 && gr < HH) {
            int f = base4 + gr * ROW4 + tcg;
            if (P0) {
                // u(1) = thresh(ga, rc) computed from x,y (div(p0)=0)
                float gx[4], gy[4], rcv[4];
                garc_row(xg, yg, f, gr, tc, gx, gy, rcv);
                float v1[4], v2[4];
                #pragma unroll
                for (int k = 0; k < 4; ++k) {
                    float grad = fmaf(gx[k], gx[k], fmaf(gy[k], gy[k], EPSF));
                    float rho  = rcv[k] + EPSF;           // u = 0
                    thresh(gx[k], gy[k], rho, grad, l_t, v1[k], v2[k]);
                }
                *dst = pack4h2(v1, v2);
            } else {
                *dst = ((const float4*)upi)[f];           // raw fp16 copy
            }
        } else {
            *dst = make_float4(0.f, 0.f, 0.f, 0.f);
        }
    }
    __syncthreads();

    #pragma unroll
    for (int m = 0; m < NIT; ++m) {
        // ===== p-step m: p(k+m) at rows [-(NIT-m), FTRH-1+(NIT-1-m)] =====
        const int plo = -(NIT - m);
        const int phi = FTRH - 1 + (NIT - 1 - m);
        #pragma unroll
        for (int pass = 0; pass < 2; ++pass) {
            int rr = tr + plo + pass * FTRH;
            if (rr > phi) continue;                // wave-uniform guard
            int gr = i0 + rr;
            int li = rr + NIT;
            if (gr >= 0 && gr < HH) {
                float4 rawU = *(const float4*)&sU[li][tc];
                float u1c[4], u2c[4];
                unpack4h2(rawU, u1c, u2c);
                float u1d[4] = {0,0,0,0}, u2d[4] = {0,0,0,0};
                bool hasDn = (gr < HH - 1);
                if (hasDn) unpack4h2(*(const float4*)&sU[li + 1][tc], u1d, u2d);
                // right-neighbor px from lane+1 (word 0 of its rawU)
                unsigned int w0 = ((const unsigned int*)&rawU)[0];
                unsigned int nb = __shfl_down((int)w0, 1);
                float u1r, u2r;  h2w(nb, u1r, u2r);   // lane 63 unused
                float c11[4], c12[4], c21[4], c22[4];
                if (m == 0) {
                    if (P0) {
                        #pragma unroll
                        for (int k = 0; k < 4; ++k) { c11[k]=c12[k]=c21[k]=c22[k]=0.f; }
                    } else {
                        int f = base4 + gr * ROW4 + tcg;
                        ld8h(pai, f, c11, c12);
                        ld8h(pbi, f, c21, c22);
                    }
                } else {
                    unpack4h2(*(const float4*)&sPA[li][tc], c11, c21);
                    unpack4h2(*(const float4*)&sPB[li][tc], c12, c22);
                }
                float p11n[4], p12n[4], p21n[4], p22n[4];
                #pragma unroll
                for (int k = 0; k < 4; ++k) {
                    int j = tc + k;
                    float du1 = (k < 3) ? u1c[k + 1] : u1r;
                    float du2 = (k < 3) ? u2c[k + 1] : u2r;
                    float u1x = (j < WW - 1) ? du1 - u1c[k] : 0.f;
                    float u2x = (j < WW - 1) ? du2 - u2c[k] : 0.f;
                    float u1y = hasDn ? u1d[k] - u1c[k] : 0.f;
                    float u2y = hasDn ? u2d[k] - u2c[k] : 0.f;
                    pupd(c11[k], c12[k], u1x, u1y, taut, p11n[k], p12n[k]);
                    pupd(c21[k], c22[k], u2x, u2y, taut, p21n[k], p22n[k]);
                }
                *(float4*)&sPA[li][tc] = pack4h2(p11n, p21n);
                *(float4*)&sPB[li][tc] = pack4h2(p12n, p22n);
                if (m == NIT - 1 && !LAST && rr >= 0 && rr < FTRH) {
                    int f = base4 + gr * ROW4 + tcg;
                    st8h(pao, f, p11n, p12n);
                    st8h(pbo, f, p21n, p22n);
                }
            } else {
                *(float4*)&sPA[li][tc] = make_float4(0.f, 0.f, 0.f, 0.f);
                *(float4*)&sPB[li][tc] = make_float4(0.f, 0.f, 0.f, 0.f);
            }
        }
        __syncthreads();

        // ===== u-step m: u(k+m+1) at rows [-(NIT-1-m), FTRH-1+(NIT-1-m)] =====
        const int ulo = -(NIT - 1 - m);
        const int uhi = FTRH - 1 + (NIT - 1 - m);
        #pragma unroll
        for (int pass = 0; pass < 2; ++pass) {
            int rr = tr + ulo + pass * FTRH;
            if (rr > uhi) continue;                // wave-uniform guard
            int gr = i0 + rr;
            int li = rr + NIT;
            if (gr < 0 || gr >= HH) continue;      // out-of-image rows stay 0
            int f = base4 + gr * ROW4 + tcg;
            // ga/rc recomputed from x,y every time (pure function; x,y is
            // L3-resident and L2-local under the XCD swizzle)
            float gx[4], gy[4], rcv[4];
            garc_row(xg, yg, f, gr, tc, gx, gy, rcv);
            float u1c[4], u2c[4];
            unpack4h2(*(const float4*)&sU[li][tc], u1c, u2c);
            float4 rawA = *(const float4*)&sPA[li][tc];
            float p11[4], p21[4], p12[4], p22[4], q12[4], q22[4];
            unpack4h2(rawA, p11, p21);
            unpack4h2(*(const float4*)&sPB[li][tc], p12, p22);
            unpack4h2(*(const float4*)&sPB[li - 1][tc], q12, q22);   // row r-1
            // left-neighbor px from lane-1 (word 3 of its rawA)
            unsigned int w3 = ((const unsigned int*)&rawA)[3];
            unsigned int lw = __shfl_up((int)w3, 1);
            float l11, l21;  h2w(lw, l11, l21);
            if (tcg == 0) { l11 = 0.f; l21 = 0.f; }   // j==0 boundary
            bool hasDn = (gr < HH - 1);
            float u1n[4], u2n[4];
            #pragma unroll
            for (int k = 0; k < 4; ++k) {
                int j = tc + k;
                float t11  = (j < WW - 1) ? p11[k] : 0.f;
                float t21  = (j < WW - 1) ? p21[k] : 0.f;
                float l11k = (k == 0) ? l11 : p11[k - 1];
                float l21k = (k == 0) ? l21 : p21[k - 1];
                float t12  = hasDn ? p12[k] : 0.f;
                float t22  = hasDn ? p22[k] : 0.f;
                float div1 = (t11 - l11k) + (t12 - q12[k]);
                float div2 = (t21 - l21k) + (t22 - q22[k]);

                float grad = fmaf(gx[k], gx[k], fmaf(gy[k], gy[k], EPSF));
                float rho  = rcv[k] + gx[k]*u1c[k] + gy[k]*u2c[k] + EPSF;
                float v1, v2;
                thresh(gx[k], gy[k], rho, grad, l_t, v1, v2);
                u1n[k] = v1 + u1c[k] + ts * div1;
                u2n[k] = v2 + u2c[k] + ts * div2;
            }
            if (m == NIT - 1) {
                if (LAST) { st4(u1f, f, u1n); st4(u2f, f, u2n); }
                else      { st8h(upo, f, u1n, u2n); }
            } else {
                *(float4*)&sU[li][tc] = pack4h2(u1n, u2n);   // same-px in-place
            }
        }
        if (m < NIT - 1) __syncthreads();
    }
}

// ---------------------------------------------------------------------------
extern "C" void kernel_launch(void* const* d_in, const int* in_sizes, int n_in,
                              void* d_out, int out_size, void* d_ws, size_t ws_size,
                              hipStream_t stream) {
    const float* x = (const float*)d_in[0];
    const float* y = (const float*)d_in[1];
    const float* t = (const float*)d_in[8];
    const float* l = (const float*)d_in[9];
    const float* a = (const float*)d_in[10];

    float* u1out = (float*)d_out;
    float* u2out = u1out + NPIX;

    // ws: 6 packed half2 fields = 6 * 16.8 MB = 100 MB (ga/rc eliminated)
    char* ws = (char*)d_ws;
    __half2* upA  = (__half2*)ws;                            ws += (size_t)NPIX * 4;
    __half2* upB  = (__half2*)ws;                            ws += (size_t)NPIX * 4;
    __half2* paA  = (__half2*)ws;                            ws += (size_t)NPIX * 4;
    __half2* pbA  = (__half2*)ws;                            ws += (size_t)NPIX * 4;
    __half2* paB  = (__half2*)ws;                            ws += (size_t)NPIX * 4;
    __half2* pbB  = (__half2*)ws;

    // FP1: iterations 1-3 (p1..p3, u2..u4); ga/rc from x,y; p0=0.
    fp_kernel<true, false><<<dim3(FBLK), dim3(FTHR), 0, stream>>>(
        nullptr, nullptr, nullptr,
        upA, nullptr, nullptr, paA, pbA, t, l, a,
        x, y);

    // FP2: iterations 4-6  (p4..p6, u5..u7)
    fp_kernel<false, false><<<dim3(FBLK), dim3(FTHR), 0, stream>>>(
        upA, paA, pbA,
        upB, nullptr, nullptr, paB, pbB, t, l, a,
        x, y);

    // FP3: iterations 7-9 + final u(10) as fp32; dead p(9) store skipped
    fp_kernel<false, true><<<dim3(FBLK), dim3(FTHR), 0, stream>>>(
        upB, paB, pbB,
        nullptr, u1out, u2out, nullptr, nullptr, t, l, a,
        x, y);
}

// Round 17
// 214.110 us; speedup vs baseline: 1.0388x; 1.0388x over previous
//
#include <hip/hip_runtime.h>
#include <hip/hip_fp16.h>

#define HH 256
#define WW 256
#define NB 64
#define NPIX (NB * HH * WW)      // 4,194,304 pixels
#define NF4  (NPIX / 4)          // 1,048,576 groups of 4
#define ROW4 (WW / 4)            // 64 groups per image row
#define EPSF 1e-12f
#define FTRH 8                   // output rows per tile
#define FTHR 512                 // 8 waves -> 8 rows per pass
#define TPI  (HH / FTRH)         // 32 tiles per image
#define FBLK (NB * TPI)          // 2048 blocks (FP kernel)
#define NIT  3                   // solver iterations fused per FP launch
#define NU   (FTRH + 2 * NIT)        // 14 LDS u rows
#define NPR  (FTRH + 2 * NIT - 1)    // 13 LDS p rows
// REVERT to round-15 (proven best 214.4 µs): shifting row ownership, fp16
// LDS (40 KB -> 4 blocks/CU), S fused into FP1 with ga/rc side-channel
// stores, XCD-chunked block swizzle (FETCH 56->23 MB), 2-pass unrolled
// row loops (ILP). Round-16's full ga/rc recompute in FP2/FP3 regressed
// (+8 µs): recompute-vs-load loses when the consumer is already
// VALU-bound — FP2/FP3 read the precomputed ga/rc instead.

__device__ __forceinline__ float4 ld4(const float* p, int f) {
    return ((const float4*)p)[f];
}
__device__ __forceinline__ void st4(float* p, int f, const float* v) {
    ((float4*)p)[f] = make_float4(v[0], v[1], v[2], v[3]);
}
// Packed-pair load: 4 pixels of a __half2 field (16B) -> two float[4]
__device__ __forceinline__ void ld8h(const __half2* p, int f, float* a, float* b) {
    float4 raw = ((const float4*)p)[f];
    const __half2* h = (const __half2*)&raw;
    #pragma unroll
    for (int k = 0; k < 4; ++k) {
        float2 v = __half22float2(h[k]);
        a[k] = v.x; b[k] = v.y;
    }
}
__device__ __forceinline__ void st8h(__half2* p, int f, const float* a, const float* b) {
    float4 raw;
    __half2* h = (__half2*)&raw;
    #pragma unroll
    for (int k = 0; k < 4; ++k) h[k] = __floats2half2_rn(a[k], b[k]);
    ((float4*)p)[f] = raw;
}
// Pack 4 px of two fields into 4 __half2 inside a float4 (for LDS 16B store)
__device__ __forceinline__ float4 pack4h2(const float* a, const float* b) {
    float4 raw;
    __half2* h = (__half2*)&raw;
    #pragma unroll
    for (int k = 0; k < 4; ++k) h[k] = __floats2half2_rn(a[k], b[k]);
    return raw;
}
__device__ __forceinline__ void unpack4h2(float4 raw, float* a, float* b) {
    const __half2* h = (const __half2*)&raw;
    #pragma unroll
    for (int k = 0; k < 4; ++k) {
        float2 v = __half22float2(h[k]);
        a[k] = v.x; b[k] = v.y;
    }
}
// Extract (a,b) floats from a raw 32-bit half2 word.
__device__ __forceinline__ void h2w(unsigned int w, float& a, float& b) {
    __half2 h = *(__half2*)&w;
    float2 v = __half22float2(h);
    a = v.x; b = v.y;
}

// TV-L1 thresholding step, branch-free:
//   v = med3(-rho/grad, -l_t, l_t) * g   — agrees exactly with the 3-mask
// reference logic. grad >= EPSF so rcp is safe.
__device__ __forceinline__ void thresh(
    float gx, float gy, float rho, float grad, float l_t,
    float& v1, float& v2)
{
    float s = -rho * __builtin_amdgcn_rcpf(grad);
    float c = __builtin_amdgcn_fmed3f(s, -l_t, l_t);
    v1 = c * gx; v2 = c * gy;
}

// p-pair update at one pixel for one flow (approx sqrt/rcp: err ~2^-22,
// far below the fp16 quantization every state field already pays).
__device__ __forceinline__ void pupd(
    float pao, float pbo, float ux, float uy, float taut,
    float& pa, float& pb)
{
    float n2 = fmaf(ux, ux, fmaf(uy, uy, EPSF));
    float n  = __builtin_amdgcn_sqrtf(n2);
    float r  = __builtin_amdgcn_rcpf(fmaf(taut, n, 1.f));
    pa = fmaf(taut, ux, pao) * r;
    pb = fmaf(taut, uy, pbo) * r;
}

// Compute ga=(gx,gy) (fp16-quantized) and rc=y-x (fp32) for global row gr
// from x,y. Wave spans the full row: column neighbors via shuffles.
__device__ __forceinline__ void garc_row(
    const float* __restrict__ xg, const float* __restrict__ yg,
    int f, int gr, int tc, float* gx, float* gy, float* rcv)
{
    float4 xc4 = ld4(xg, f), yc4 = ld4(yg, f);
    const float* xc = (const float*)&xc4;
    const float* yc = (const float*)&yc4;
    float4 a4, b4;                       // wave-uniform row branch
    if (gr == 0)           { a4 = ld4(xg, f + ROW4); b4 = xc4; }
    else if (gr == HH - 1) { a4 = xc4; b4 = ld4(xg, f - ROW4); }
    else                   { a4 = ld4(yg, f + ROW4); b4 = ld4(yg, f - ROW4); }
    const float* aa = (const float*)&a4;
    const float* bb = (const float*)&b4;
    float yl = __shfl_up(yc4.w, 1);      // lane 0 value unused (j==0)
    float yr = __shfl_down(yc4.x, 1);    // lane 63 value unused (j==WW-1)
    #pragma unroll
    for (int k = 0; k < 4; ++k) {
        int j = tc + k;
        float g;
        if (j == 0)            g = 0.5f * (xc[1] - xc[0]);
        else if (j == WW - 1)  g = 0.5f * (xc[3] - xc[2]);
        else {
            float ynext = (k < 3) ? yc[k + 1] : yr;
            float yprev = (k > 0) ? yc[k - 1] : yl;
            g = 0.5f * (ynext - yprev);
        }
        float gyv = 0.5f * (aa[k] - bb[k]);
        // quantize NOW so FP1's iterations match FP2/FP3's fp16 readback
        gx[k] = __half2float(__float2half_rn(g));
        gy[k] = __half2float(__float2half_rn(gyv));
        rcv[k] = yc[k] - xc[k];
    }
}

// ---------------------------------------------------------------------------
// FP: 3 fused solver iterations over an 8-row x 256-col tile with halo
// recompute, shifting row ownership. One wave owns a full row per row-pass;
// left/right px neighbors travel by lane shuffle.
//   sU  : (u1,u2) fp16x2, rows rel [-3, 10]. In-place u-update (same-px).
//   sPA : (p11,p21), sPB : (p12,p22), rows rel [-3, 9]. In-place p-update.
// All row loops are explicit 2-pass unrolled (compile-time trip count) so
// the two independent rows' chains software-pipeline.
// P0: S fused — ga/rc computed from x,y (prologue seeds u(1); u-steps
// recompute; own rows stored exactly-once for FP2/FP3); p(k-1)=0.
// LAST: final u written fp32 to d_out, dead p store skipped.
// ---------------------------------------------------------------------------
template <bool P0, bool LAST>
__global__ __launch_bounds__(FTHR, 8) void fp_kernel(
    const __half2* __restrict__ ga, const float* __restrict__ rc,
    const __half2* __restrict__ upi,
    const __half2* __restrict__ pai, const __half2* __restrict__ pbi,
    __half2* __restrict__ upo,
    float* __restrict__ u1f, float* __restrict__ u2f,
    __half2* __restrict__ pao, __half2* __restrict__ pbo,
    const float* __restrict__ tp, const float* __restrict__ lp,
    const float* __restrict__ ap,
    const float* __restrict__ xg, const float* __restrict__ yg,
    __half2* __restrict__ gao, float* __restrict__ rco)
{
    __shared__ alignas(16) __half2 sU [NU ][WW];
    __shared__ alignas(16) __half2 sPA[NPR][WW];
    __shared__ alignas(16) __half2 sPB[NPR][WW];

    const float ts   = tp[0];
    const float l_t  = lp[0] * ts;
    const float taut = ap[0] / ts;

    const int t     = threadIdx.x;
    // XCD-chunked swizzle: HW assigns blockIdx round-robin across 8 XCDs;
    // remap so each XCD gets a contiguous 256-tile chunk -> adjacent tiles
    // (which share halo rows) are co-resident in one XCD's L2. Bijective
    // (FBLK = 2048 = 8 * 256). Perf-only: any mapping is correct.
    const int bid   = blockIdx.x;
    const int tile  = ((bid & 7) << 8) | (bid >> 3);
    const int i0    = (tile & (TPI - 1)) * FTRH;   // tile top row
    const int base4 = (tile / TPI) * (HH * ROW4);  // batch offset, float4 units

    const int tr  = t >> 6;       // wave index 0..7 = row within pass
    const int tcg = t & 63;       // lane
    const int tc  = tcg * 4;

    // ---- prologue: u(k) -> sU rows [-3, 10] (2-pass unrolled) ----
    #pragma unroll
    for (int pass = 0; pass < 2; ++pass) {
        int rr = tr - NIT + pass * FTRH;
        if (rr > FTRH + NIT - 1) continue;        // wave-uniform guard
        int gr = i0 + rr;
        float4* dst = (float4*)&sU[rr + NIT][tc];
        if (gr >= 0 && gr < HH) {
            int f = base4 + gr * ROW4 + tcg;
            if (P0) {
                // fused s_kernel: ga/rc from x,y; u(1) = thresh (div(p0)=0)
                float gx[4], gy[4], rcv[4];
                garc_row(xg, yg, f, gr, tc, gx, gy, rcv);
                float v1[4], v2[4];
                #pragma unroll
                for (int k = 0; k < 4; ++k) {
                    float grad = fmaf(gx[k], gx[k], fmaf(gy[k], gy[k], EPSF));
                    float rho  = rcv[k] + EPSF;           // u = 0
                    thresh(gx[k], gy[k], rho, grad, l_t, v1[k], v2[k]);
                }
                *dst = pack4h2(v1, v2);
                // store ga/rc for FP2/FP3 (own rows only: exactly-once)
                if (rr >= 0 && rr < FTRH) {
                    st8h(gao, f, gx, gy);      // values already fp16-exact
                    st4(rco, f, rcv);
                }
            } else {
                *dst = ((const float4*)upi)[f];           // raw fp16 copy
            }
        } else {
            *dst = make_float4(0.f, 0.f, 0.f, 0.f);
        }
    }
    __syncthreads();

    #pragma unroll
    for (int m = 0; m < NIT; ++m) {
        // ===== p-step m: p(k+m) at rows [-(NIT-m), FTRH-1+(NIT-1-m)] =====
        const int plo = -(NIT - m);
        const int phi = FTRH - 1 + (NIT - 1 - m);
        #pragma unroll
        for (int pass = 0; pass < 2; ++pass) {
            int rr = tr + plo + pass * FTRH;
            if (rr > phi) continue;                // wave-uniform guard
            int gr = i0 + rr;
            int li = rr + NIT;
            if (gr >= 0 && gr < HH) {
                float4 rawU = *(const float4*)&sU[li][tc];
                float u1c[4], u2c[4];
                unpack4h2(rawU, u1c, u2c);
                float u1d[4] = {0,0,0,0}, u2d[4] = {0,0,0,0};
                bool hasDn = (gr < HH - 1);
                if (hasDn) unpack4h2(*(const float4*)&sU[li + 1][tc], u1d, u2d);
                // right-neighbor px from lane+1 (word 0 of its rawU)
                unsigned int w0 = ((const unsigned int*)&rawU)[0];
                unsigned int nb = __shfl_down((int)w0, 1);
                float u1r, u2r;  h2w(nb, u1r, u2r);   // lane 63 unused
                float c11[4], c12[4], c21[4], c22[4];
                if (m == 0) {
                    if (P0) {
                        #pragma unroll
                        for (int k = 0; k < 4; ++k) { c11[k]=c12[k]=c21[k]=c22[k]=0.f; }
                    } else {
                        int f = base4 + gr * ROW4 + tcg;
                        ld8h(pai, f, c11, c12);
                        ld8h(pbi, f, c21, c22);
                    }
                } else {
                    unpack4h2(*(const float4*)&sPA[li][tc], c11, c21);
                    unpack4h2(*(const float4*)&sPB[li][tc], c12, c22);
                }
                float p11n[4], p12n[4], p21n[4], p22n[4];
                #pragma unroll
                for (int k = 0; k < 4; ++k) {
                    int j = tc + k;
                    float du1 = (k < 3) ? u1c[k + 1] : u1r;
                    float du2 = (k < 3) ? u2c[k + 1] : u2r;
                    float u1x = (j < WW - 1) ? du1 - u1c[k] : 0.f;
                    float u2x = (j < WW - 1) ? du2 - u2c[k] : 0.f;
                    float u1y = hasDn ? u1d[k] - u1c[k] : 0.f;
                    float u2y = hasDn ? u2d[k] - u2c[k] : 0.f;
                    pupd(c11[k], c12[k], u1x, u1y, taut, p11n[k], p12n[k]);
                    pupd(c21[k], c22[k], u2x, u2y, taut, p21n[k], p22n[k]);
                }
                *(float4*)&sPA[li][tc] = pack4h2(p11n, p21n);
                *(float4*)&sPB[li][tc] = pack4h2(p12n, p22n);
                if (m == NIT - 1 && !LAST && rr >= 0 && rr < FTRH) {
                    int f = base4 + gr * ROW4 + tcg;
                    st8h(pao, f, p11n, p12n);
                    st8h(pbo, f, p21n, p22n);
                }
            } else {
                *(float4*)&sPA[li][tc] = make_float4(0.f, 0.f, 0.f, 0.f);
                *(float4*)&sPB[li][tc] = make_float4(0.f, 0.f, 0.f, 0.f);
            }
        }
        __syncthreads();

        // ===== u-step m: u(k+m+1) at rows [-(NIT-1-m), FTRH-1+(NIT-1-m)] =====
        const int ulo = -(NIT - 1 - m);
        const int uhi = FTRH - 1 + (NIT - 1 - m);
        #pragma unroll
        for (int pass = 0; pass < 2; ++pass) {
            int rr = tr + ulo + pass * FTRH;
            if (rr > uhi) continue;                // wave-uniform guard
            int gr = i0 + rr;
            int li = rr + NIT;
            if (gr < 0 || gr >= HH) continue;      // out-of-image rows stay 0
            int f = base4 + gr * ROW4 + tcg;
            float gx[4], gy[4], rcv[4];
            if (P0) {
                // recompute from x,y: pure function of inputs -> no race
                // with this launch's own ga/rc stores (L2-resident reads)
                garc_row(xg, yg, f, gr, tc, gx, gy, rcv);
            } else {
                ld8h(ga, f, gx, gy);              // halo re-reads hit L1/L2
                float4 rc4 = ld4(rc, f);
                rcv[0]=rc4.x; rcv[1]=rc4.y; rcv[2]=rc4.z; rcv[3]=rc4.w;
            }
            float u1c[4], u2c[4];
            unpack4h2(*(const float4*)&sU[li][tc], u1c, u2c);
            float4 rawA = *(const float4*)&sPA[li][tc];
            float p11[4], p21[4], p12[4], p22[4], q12[4], q22[4];
            unpack4h2(rawA, p11, p21);
            unpack4h2(*(const float4*)&sPB[li][tc], p12, p22);
            unpack4h2(*(const float4*)&sPB[li - 1][tc], q12, q22);   // row r-1
            // left-neighbor px from lane-1 (word 3 of its rawA)
            unsigned int w3 = ((const unsigned int*)&rawA)[3];
            unsigned int lw = __shfl_up((int)w3, 1);
            float l11, l21;  h2w(lw, l11, l21);
            if (tcg == 0) { l11 = 0.f; l21 = 0.f; }   // j==0 boundary
            bool hasDn = (gr < HH - 1);
            float u1n[4], u2n[4];
            #pragma unroll
            for (int k = 0; k < 4; ++k) {
                int j = tc + k;
                float t11  = (j < WW - 1) ? p11[k] : 0.f;
                float t21  = (j < WW - 1) ? p21[k] : 0.f;
                float l11k = (k == 0) ? l11 : p11[k - 1];
                float l21k = (k == 0) ? l21 : p21[k - 1];
                float t12  = hasDn ? p12[k] : 0.f;
                float t22  = hasDn ? p22[k] : 0.f;
                float div1 = (t11 - l11k) + (t12 - q12[k]);
                float div2 = (t21 - l21k) + (t22 - q22[k]);

                float grad = fmaf(gx[k], gx[k], fmaf(gy[k], gy[k], EPSF));
                float rho  = rcv[k] + gx[k]*u1c[k] + gy[k]*u2c[k] + EPSF;
                float v1, v2;
                thresh(gx[k], gy[k], rho, grad, l_t, v1, v2);
                u1n[k] = v1 + u1c[k] + ts * div1;
                u2n[k] = v2 + u2c[k] + ts * div2;
            }
            if (m == NIT - 1) {
                if (LAST) { st4(u1f, f, u1n); st4(u2f, f, u2n); }
                else      { st8h(upo, f, u1n, u2n); }
            } else {
                *(float4*)&sU[li][tc] = pack4h2(u1n, u2n);   // same-px in-place
            }
        }
        if (m < NIT - 1) __syncthreads();
    }
}

// ---------------------------------------------------------------------------
extern "C" void kernel_launch(void* const* d_in, const int* in_sizes, int n_in,
                              void* d_out, int out_size, void* d_ws, size_t ws_size,
                              hipStream_t stream) {
    const float* x = (const float*)d_in[0];
    const float* y = (const float*)d_in[1];
    const float* t = (const float*)d_in[8];
    const float* l = (const float*)d_in[9];
    const float* a = (const float*)d_in[10];

    float* u1out = (float*)d_out;
    float* u2out = u1out + NPIX;

    // ws: rc(f32) + 7 packed half2 fields = 8 * 16.8 MB = 134 MB
    char* ws = (char*)d_ws;
    float*   rcp_ = (float*)ws;                              ws += (size_t)NPIX * 4;
    __half2* gaP  = (__half2*)ws;                            ws += (size_t)NPIX * 4;
    __half2* upA  = (__half2*)ws;                            ws += (size_t)NPIX * 4;
    __half2* upB  = (__half2*)ws;                            ws += (size_t)NPIX * 4;
    __half2* paA  = (__half2*)ws;                            ws += (size_t)NPIX * 4;
    __half2* pbA  = (__half2*)ws;                            ws += (size_t)NPIX * 4;
    __half2* paB  = (__half2*)ws;                            ws += (size_t)NPIX * 4;
    __half2* pbB  = (__half2*)ws;

    // FP1 (S fused): iterations 1-3 (p1..p3, u2..u4); ga/rc computed from
    // x,y in-kernel and stored for FP2/FP3; p0 = 0, u1 in-register.
    fp_kernel<true, false><<<dim3(FBLK), dim3(FTHR), 0, stream>>>(
        gaP, rcp_, nullptr, nullptr, nullptr,
        upA, nullptr, nullptr, paA, pbA, t, l, a,
        x, y, gaP, rcp_);

    // FP2: iterations 4-6  (p4..p6, u5..u7)
    fp_kernel<false, false><<<dim3(FBLK), dim3(FTHR), 0, stream>>>(
        gaP, rcp_, upA, paA, pbA,
        upB, nullptr, nullptr, paB, pbB, t, l, a,
        nullptr, nullptr, nullptr, nullptr);

    // FP3: iterations 7-9 + final u(10) as fp32; dead p(9) store skipped
    fp_kernel<false, true><<<dim3(FBLK), dim3(FTHR), 0, stream>>>(
        gaP, rcp_, upB, paB, pbB,
        nullptr, u1out, u2out, nullptr, nullptr, t, l, a,
        nullptr, nullptr, nullptr, nullptr);
}